// Round 12
// baseline (105.122 us; speedup 1.0000x reference)
//
#include <hip/hip_runtime.h>
#include <math.h>

// Problem geometry (fixed): B=4, N=16, K=16, H=64, O=1
// W: (a,b,d,e,k,o) = 16^4 x 16 x 64 fp32 = 256 MiB.
//
// h[z,a,o] = sum_{j=(b,d,e,k)} P[z,a,j] * W[a,j,o]
// P[z,a,j] = sum_c basis[z,a,b,k,c] * basis[z,d,e,k,c]
// out[z,a] = silu(h[z,a,:]) . w_fc + b_fc
//
// Cosine cutoff (dist>=5) kills ~70% of pairs exactly -> ~65% of W rows
// have P==0 for all z; their loads are skipped (bit-exact).
//
// R11 structure:
//  - k_basis precomputes basisv[z][p][q][k] (256 KB, L2-hot) ONCE; the
//    main kernel's per-item prologue is 8 vector loads + dot3s (no
//    transcendentals) -> small work items are cheap.
//  - k_main is a persistent-block ATOMIC WORK QUEUE: 2048 blocks drain
//    4096 items (item = (a,b,d), 256 W-rows). Deterministic: each item
//    writes only part[item]; executor identity doesn't matter. Counter
//    reset per launch via 4-byte hipMemsetAsync (graph-capturable).
//
// ws layout (floats):
//   part   : [4096][256]  = 1,048,576 floats @ 0        (4 MB)
//   basisv : f32x4[16384] =    65,536 floats @ 1048576  (256 KB)
//   counter: 1 uint       @ float offset 1,114,112

#define NJ 65536
#define NITEMS 4096
#define GRID_MAIN 2048

typedef float f32x4 __attribute__((ext_vector_type(4)));

static constexpr double D_START = 0.006737946999085467; // exp(-5)

__global__ void k_basis(const float* __restrict__ x, f32x4* __restrict__ basisv) {
    int t = blockIdx.x * blockDim.x + threadIdx.x; // (z,p,q): 4*16*16 = 1024
    if (t >= 1024) return;
    int q = t & 15, p = (t >> 4) & 15, z = t >> 8;
    const float* xp = x + (z * 16 + p) * 3;
    const float* xq = x + (z * 16 + q) * 3;
    float d0 = xp[0] - xq[0], d1 = xp[1] - xq[1], d2 = xp[2] - xq[2];
    float nsq = d0 * d0 + d1 * d1 + d2 * d2 + 1e-5f;
    float nrm = sqrtf(nsq);
    f32x4* o = basisv + (size_t)t * 16;
    if (nrm >= 5.0f) {                       // cutoff kills the pair exactly
        f32x4 zv = {0.f, 0.f, 0.f, 0.f};
        #pragma unroll
        for (int k = 0; k < 16; ++k) o[k] = zv;
        return;
    }
    float cut = 0.5f * (cosf(nrm * 0.6283185307179586f) + 1.0f);
    float ex = expf(-nrm); // alpha=1, CUT_LO=0
    const float START = (float)D_START;
    const float STEP  = (float)((1.0 - D_START) / 15.0);
    const float BETA  = (float)(1.0 / ((0.125 * (1.0 - D_START)) * (0.125 * (1.0 - D_START))));
    #pragma unroll
    for (int k = 0; k < 16; ++k) {
        float m = START + STEP * (float)k;
        float dmm = ex - m;
        float s = cut * expf(-BETA * dmm * dmm) / nsq; // fold /nsq of diff in
        f32x4 v; v.x = s * d0; v.y = s * d1; v.z = s * d2; v.w = 0.f;
        o[k] = v;
    }
}

__global__ __launch_bounds__(256) void k_main(const f32x4* __restrict__ W4,
                                              const f32x4* __restrict__ basisv,
                                              float* __restrict__ part,
                                              unsigned* __restrict__ counter) {
    __shared__ f32x4 p_lds[256];
    __shared__ float red[4][256];
    __shared__ unsigned s_item;

    int t    = threadIdx.x;
    int wave = t >> 6;
    int lane = t & 63;
    int og   = lane & 15;  // group of 4 'o' columns
    int rsub = lane >> 4;  // row within the 4-row group

    while (true) {
        if (t == 0) s_item = atomicAdd(counter, 1u);
        __syncthreads();
        unsigned item = s_item;
        if (item >= NITEMS) break;           // uniform exit

        int a = item >> 8, blk = item & 255;
        int b = blk >> 4, d = blk & 15;

        // ---- prologue: P for this item's 256 rows, from basisv ----
        int e = t >> 4, k = t & 15;
        f32x4 p0;
        #pragma unroll
        for (int z = 0; z < 4; ++z) {
            f32x4 u = basisv[(((z * 16 + a) * 16 + b) * 16) + k];
            f32x4 v = basisv[(((z * 16 + d) * 16 + e) * 16) + k];
            p0[z] = u.x * v.x + u.y * v.y + u.z * v.z;
        }
        bool alive = (fabsf(p0.x) + fabsf(p0.y) + fabsf(p0.z) + fabsf(p0.w)) != 0.0f;
        unsigned long long bal = __ballot(alive);
        p_lds[t] = p0;                       // wave-local span (in-order LDS)

        unsigned mask = 0;
        #pragma unroll
        for (int g = 0; g < 8; ++g)
            if ((bal >> (8 * g)) & 0xFFull) mask |= 1u << g;

        float acc[4][4] = {{0.f, 0.f, 0.f, 0.f}, {0.f, 0.f, 0.f, 0.f},
                           {0.f, 0.f, 0.f, 0.f}, {0.f, 0.f, 0.f, 0.f}};
        size_t rowbase = (size_t)a * NJ + (size_t)blk * 256;
        while (mask) {                       // wave-uniform (ballot-derived)
            int g = __builtin_ctz(mask);
            mask &= mask - 1;
            int rloc = wave * 64 + g * 8 + rsub;
            f32x4 pA = p_lds[rloc];
            f32x4 pB = p_lds[rloc + 4];
            f32x4 wA = W4[(rowbase + rloc) * 16 + og];       // 1 KB/wave
            f32x4 wB = W4[(rowbase + rloc + 4) * 16 + og];   // 1 KB/wave
            acc[0][0] += pA.x * wA.x + pB.x * wB.x; acc[0][1] += pA.x * wA.y + pB.x * wB.y;
            acc[0][2] += pA.x * wA.z + pB.x * wB.z; acc[0][3] += pA.x * wA.w + pB.x * wB.w;
            acc[1][0] += pA.y * wA.x + pB.y * wB.x; acc[1][1] += pA.y * wA.y + pB.y * wB.y;
            acc[1][2] += pA.y * wA.z + pB.y * wB.z; acc[1][3] += pA.y * wA.w + pB.y * wB.w;
            acc[2][0] += pA.z * wA.x + pB.z * wB.x; acc[2][1] += pA.z * wA.y + pB.z * wB.y;
            acc[2][2] += pA.z * wA.z + pB.z * wB.z; acc[2][3] += pA.z * wA.w + pB.z * wB.w;
            acc[3][0] += pA.w * wA.x + pB.w * wB.x; acc[3][1] += pA.w * wA.y + pB.w * wB.y;
            acc[3][2] += pA.w * wA.z + pB.w * wB.z; acc[3][3] += pA.w * wA.w + pB.w * wB.w;
        }
        // reduce across the 4 row-subgroups (lane bits 4,5)
        #pragma unroll
        for (int z = 0; z < 4; ++z) {
            #pragma unroll
            for (int c = 0; c < 4; ++c) {
                float v = acc[z][c];
                v += __shfl_xor(v, 16);
                v += __shfl_xor(v, 32);
                acc[z][c] = v;
            }
        }
        if (rsub == 0) {
            #pragma unroll
            for (int z = 0; z < 4; ++z) {
                #pragma unroll
                for (int c = 0; c < 4; ++c)
                    red[wave][z * 64 + og * 4 + c] = acc[z][c];
            }
        }
        __syncthreads();
        float s = red[0][t] + red[1][t] + red[2][t] + red[3][t];
        part[(size_t)item * 256 + t] = s;
        // next iteration's top barrier orders red reuse
    }
}

__global__ void k_out(const float* __restrict__ part, const float* __restrict__ w_fc,
                      const float* __restrict__ b_fc, float* __restrict__ out) {
    // one block per (z,a); 256 threads = 4 item-quarters x 64 'o'
    int z = blockIdx.x >> 4, a = blockIdx.x & 15;
    int o = threadIdx.x & 63, bq = threadIdx.x >> 6;
    float s = 0.f;
    for (int blk = bq; blk < 256; blk += 4)
        s += part[((size_t)a * 256 + blk) * 256 + z * 64 + o]; // coalesced over o
    __shared__ float red[4][64];
    red[bq][o] = s;
    __syncthreads();
    if (threadIdx.x < 64) {
        float h = red[0][o] + red[1][o] + red[2][o] + red[3][o];
        float v = h * (1.0f / (1.0f + expf(-h))) * w_fc[o]; // silu * weight
        #pragma unroll
        for (int off = 32; off >= 1; off >>= 1) v += __shfl_xor(v, off);
        if (o == 0) out[z * 16 + a] = v + b_fc[0];
    }
}

extern "C" void kernel_launch(void* const* d_in, const int* in_sizes, int n_in,
                              void* d_out, int out_size, void* d_ws, size_t ws_size,
                              hipStream_t stream) {
    const float* x    = (const float*)d_in[0];
    const float* W    = (const float*)d_in[1];
    const float* w_fc = (const float*)d_in[2];
    const float* b_fc = (const float*)d_in[3];
    float* ws  = (float*)d_ws;
    float* out = (float*)d_out;

    float*    part    = ws;                         // 1,048,576 floats
    f32x4*    basisv  = (f32x4*)(ws + 1048576);     // 65,536 floats
    unsigned* counter = (unsigned*)(ws + 1114112);  // 1 uint

    (void)hipMemsetAsync((void*)counter, 0, 4, stream);
    k_basis<<<4, 256, 0, stream>>>(x, basisv);
    k_main<<<GRID_MAIN, 256, 0, stream>>>((const f32x4*)W, basisv, part, counter);
    k_out<<<64, 256, 0, stream>>>(part, w_fc, b_fc, out);
}

// Round 13
// 43.337 us; speedup vs baseline: 2.4257x; 2.4257x over previous
//
#include <hip/hip_runtime.h>
#include <math.h>

// B=4, N=16, K=16, H=64, O=1.  W: (a,b,d,e,k,o) fp32 = 256 MiB.
// h[z,a,o] = sum_j P[z,a,j] W[a,j,o];  P from basis pairs; out = silu(h).w_fc+b.
//
// Group = (a,b,d,e) x k(0..15) = 16 rows = 4 KB of W. Group alive iff
// exists z: pair(a,b,z) and pair(d,e,z) both inside the cosine cutoff
// (k-independent). Only alive groups are touched (bit-exact skip).
//
// Pipeline (all deterministic, no atomics):
//   k_basis : basisv table (256 KB) + per-(z,p,q) alive flags
//   k_list  : per-a prefix-sum compaction of alive (b,d,e) codes -> glist,
//             cnt[a]
//   k_main  : fixed 2064 blocks; blocks allotted to each a proportional to
//             cnt[a] (same integer formula recomputed everywhere); each
//             block processes its groups in 16-group chunks:
//             prologue (P -> LDS, 1 task/thread) + inner (1 KB/wave/group)
//   k_out   : per (z,a) reduce part rows of a's block range, silu, dot.
//
// ws (floats):
//   part   : [2064][256]   @ 0        (528384 f)
//   basisv : f32x4[16384]  @ 528384   (65536 f)
//   flags  : u8[1024]      @ 593920   (256 f)
//   cnt    : u32[16]       @ 594176   (16 f)
//   glist  : u32[65536]    @ 594192   (65536 f)

#define NBLK_TARGET 2048
#define GRID_MAIN   2064   // 2048 + up to 16 rounding bumps
#define CH 16

typedef float f32x4 __attribute__((ext_vector_type(4)));
typedef unsigned int u32;

static constexpr double D_START = 0.006737946999085467; // exp(-5)

__global__ void k_basis(const float* __restrict__ x, f32x4* __restrict__ basisv,
                        unsigned char* __restrict__ flags) {
    int t = blockIdx.x * 256 + threadIdx.x; // (z,p,q)
    if (t >= 1024) return;
    int q = t & 15, p = (t >> 4) & 15, z = t >> 8;
    const float* xp = x + (z * 16 + p) * 3;
    const float* xq = x + (z * 16 + q) * 3;
    float d0 = xp[0] - xq[0], d1 = xp[1] - xq[1], d2 = xp[2] - xq[2];
    float nsq = d0 * d0 + d1 * d1 + d2 * d2 + 1e-5f;
    float nrm = sqrtf(nsq);
    bool alive = (nrm < 5.0f) && (d0 != 0.f || d1 != 0.f || d2 != 0.f);
    flags[t] = alive ? 1 : 0;
    f32x4* o = basisv + (size_t)t * 16;
    if (!alive) {
        f32x4 zv = {0.f, 0.f, 0.f, 0.f};
        #pragma unroll
        for (int k = 0; k < 16; ++k) o[k] = zv;
        return;
    }
    float cut = 0.5f * (cosf(nrm * 0.6283185307179586f) + 1.0f);
    float ex = expf(-nrm);
    const float START = (float)D_START;
    const float STEP  = (float)((1.0 - D_START) / 15.0);
    const float BETA  = (float)(1.0 / ((0.125 * (1.0 - D_START)) * (0.125 * (1.0 - D_START))));
    #pragma unroll
    for (int k = 0; k < 16; ++k) {
        float m = START + STEP * (float)k;
        float dmm = ex - m;
        float s = cut * expf(-BETA * dmm * dmm) / nsq; // /nsq of diff folded in
        f32x4 v; v.x = s * d0; v.y = s * d1; v.z = s * d2; v.w = 0.f;
        o[k] = v;
    }
}

// 16 blocks (one per a), 256 threads: compact alive (b,d,e) codes.
__global__ __launch_bounds__(256) void k_list(const unsigned char* __restrict__ flags,
                                              u32* __restrict__ glist,
                                              u32* __restrict__ cnt) {
    int a = blockIdx.x;
    int t = threadIdx.x;
    __shared__ unsigned char deZ[256];
    __shared__ u32 scnt[256];
    deZ[t] = (unsigned char)(flags[t] | (flags[256 + t] << 1) |
                             (flags[512 + t] << 2) | (flags[768 + t] << 3));
    __syncthreads();
    int b = t >> 4, c16 = (t & 15) << 4;   // covers de = c16..c16+15
    unsigned abm = deZ[a * 16 + b];
    unsigned bits = 0;
    #pragma unroll
    for (int i = 0; i < 16; ++i)
        if (abm & deZ[c16 + i]) bits |= 1u << i;
    u32 mycnt = __popc(bits);
    scnt[t] = mycnt;
    __syncthreads();
    for (int off = 1; off < 256; off <<= 1) {   // inclusive Hillis-Steele
        u32 u = (t >= off) ? scnt[t - off] : 0;
        __syncthreads();
        scnt[t] += u;
        __syncthreads();
    }
    u32 excl = scnt[t] - mycnt;
    u32 woff = (u32)a * 4096u + excl;
    #pragma unroll
    for (int i = 0; i < 16; ++i)
        if ((bits >> i) & 1u) glist[woff++] = (u32)((b << 8) | (c16 + i));
    if (t == 255) cnt[a] = scnt[255];
}

__global__ __launch_bounds__(256) void k_main(const f32x4* __restrict__ W4,
                                              const f32x4* __restrict__ basisv,
                                              const u32* __restrict__ glist,
                                              const u32* __restrict__ cnt,
                                              float* __restrict__ part) {
    __shared__ u32 s_cnt[16];
    __shared__ u32 s_codes[CH];
    __shared__ f32x4 p_lds[CH * 16];
    __shared__ float red[4][256];

    int t = threadIdx.x;
    if (t < 16) s_cnt[t] = cnt[t];
    __syncthreads();
    u32 total = 0;
    #pragma unroll
    for (int i = 0; i < 16; ++i) total += s_cnt[i];
    u32 bi = blockIdx.x;
    u32 accb = 0, local = 0, cnta = 0, nba = 0;
    int mya = -1;
    #pragma unroll
    for (int i = 0; i < 16; ++i) {
        u32 ci = s_cnt[i];
        u32 nb = 1;
        if (total) {
            nb = (u32)(((unsigned long long)ci * NBLK_TARGET) / total);
            if (!nb) nb = 1;
        }
        if (bi >= accb && bi < accb + nb) { mya = i; local = bi - accb; cnta = ci; nba = nb; }
        accb += nb;
    }
    if (mya < 0) return;                 // beyond used blocks; never read
    u32 gpb = nba ? (cnta + nba - 1) / nba : 0;
    u32 g0 = local * gpb;
    u32 g1 = g0 + gpb; if (g1 > cnta) g1 = cnta;
    int a = mya;
    u32 base = (u32)a * 4096u;

    int wave = t >> 6, lane = t & 63, og = lane & 15, rsub = lane >> 4;
    int myk = t >> 4;                    // 0..15
    float acc[4][4] = {{0.f,0.f,0.f,0.f},{0.f,0.f,0.f,0.f},
                       {0.f,0.f,0.f,0.f},{0.f,0.f,0.f,0.f}};
    size_t wbase = (size_t)a << 16;      // a*65536 rows

    for (u32 ch = g0; ch < g1; ch += CH) {
        int n = (int)((g1 - ch < CH) ? (g1 - ch) : CH);
        __syncthreads();                 // p_lds reuse guard
        int pg = t >> 4, kk = t & 15;
        if (pg < n) {
            u32 code = glist[base + ch + pg];
            if (kk == 0) s_codes[pg] = code;
            int b = (int)(code >> 8), de = (int)(code & 255);
            f32x4 p;
            #pragma unroll
            for (int z = 0; z < 4; ++z) {
                f32x4 u = basisv[((z * 256) + a * 16 + b) * 16 + kk];
                f32x4 v = basisv[((z * 256) + de) * 16 + kk];
                p[z] = u.x * v.x + u.y * v.y + u.z * v.z;
            }
            p_lds[pg * 16 + kk] = p;
        }
        __syncthreads();
        for (int g = 0; g < n; ++g) {
            u32 code = s_codes[g];
            u32 j = (code << 4) | (u32)myk;
            f32x4 p4 = p_lds[g * 16 + myk];
            f32x4 w4 = W4[(wbase + j) * 16 + og];   // wave: 1 KB contiguous
            acc[0][0] += p4.x * w4.x; acc[0][1] += p4.x * w4.y;
            acc[0][2] += p4.x * w4.z; acc[0][3] += p4.x * w4.w;
            acc[1][0] += p4.y * w4.x; acc[1][1] += p4.y * w4.y;
            acc[1][2] += p4.y * w4.z; acc[1][3] += p4.y * w4.w;
            acc[2][0] += p4.z * w4.x; acc[2][1] += p4.z * w4.y;
            acc[2][2] += p4.z * w4.z; acc[2][3] += p4.z * w4.w;
            acc[3][0] += p4.w * w4.x; acc[3][1] += p4.w * w4.y;
            acc[3][2] += p4.w * w4.z; acc[3][3] += p4.w * w4.w;
        }
    }
    // reduce over the 16 k-lanes: xor16+xor32 within wave, LDS across waves
    #pragma unroll
    for (int z = 0; z < 4; ++z) {
        #pragma unroll
        for (int c = 0; c < 4; ++c) {
            float v = acc[z][c];
            v += __shfl_xor(v, 16);
            v += __shfl_xor(v, 32);
            acc[z][c] = v;
        }
    }
    if (rsub == 0) {
        #pragma unroll
        for (int z = 0; z < 4; ++z) {
            #pragma unroll
            for (int c = 0; c < 4; ++c)
                red[wave][z * 64 + og * 4 + c] = acc[z][c];
        }
    }
    __syncthreads();
    float s = red[0][t] + red[1][t] + red[2][t] + red[3][t];
    part[(size_t)bi * 256 + t] = s;
}

__global__ void k_out(const float* __restrict__ part, const u32* __restrict__ cnt,
                      const float* __restrict__ w_fc, const float* __restrict__ b_fc,
                      float* __restrict__ out) {
    int z = blockIdx.x >> 4, a = blockIdx.x & 15;
    int o = threadIdx.x & 63, bq = threadIdx.x >> 6;
    __shared__ u32 s_cnt[16];
    if (threadIdx.x < 16) s_cnt[threadIdx.x] = cnt[threadIdx.x];
    __syncthreads();
    u32 total = 0;
    #pragma unroll
    for (int i = 0; i < 16; ++i) total += s_cnt[i];
    u32 accb = 0, r0 = 0, r1 = 0;
    #pragma unroll
    for (int i = 0; i < 16; ++i) {      // must match k_main exactly
        u32 ci = s_cnt[i];
        u32 nb = 1;
        if (total) {
            nb = (u32)(((unsigned long long)ci * NBLK_TARGET) / total);
            if (!nb) nb = 1;
        }
        if (i == a) { r0 = accb; r1 = accb + nb; }
        accb += nb;
    }
    float s = 0.f;
    for (u32 blk = r0 + (u32)bq; blk < r1; blk += 4)
        s += part[(size_t)blk * 256 + z * 64 + o];  // coalesced over o
    __shared__ float red[4][64];
    red[bq][o] = s;
    __syncthreads();
    if (threadIdx.x < 64) {
        float h = red[0][o] + red[1][o] + red[2][o] + red[3][o];
        float v = h * (1.0f / (1.0f + expf(-h))) * w_fc[o]; // silu * weight
        #pragma unroll
        for (int off = 32; off >= 1; off >>= 1) v += __shfl_xor(v, off);
        if (o == 0) out[z * 16 + a] = v + b_fc[0];
    }
}

extern "C" void kernel_launch(void* const* d_in, const int* in_sizes, int n_in,
                              void* d_out, int out_size, void* d_ws, size_t ws_size,
                              hipStream_t stream) {
    const float* x    = (const float*)d_in[0];
    const float* W    = (const float*)d_in[1];
    const float* w_fc = (const float*)d_in[2];
    const float* b_fc = (const float*)d_in[3];
    float* ws  = (float*)d_ws;
    float* out = (float*)d_out;

    float*         part   = ws;                              // 528,384 f
    f32x4*         basisv = (f32x4*)(ws + 528384);           // 65,536 f
    unsigned char* flags  = (unsigned char*)(ws + 593920);   // 1,024 B
    u32*           cnt    = (u32*)(ws + 594176);             // 16 u32
    u32*           glist  = (u32*)(ws + 594192);             // 65,536 u32

    k_basis<<<4, 256, 0, stream>>>(x, basisv, flags);
    k_list<<<16, 256, 0, stream>>>(flags, glist, cnt);
    k_main<<<GRID_MAIN, 256, 0, stream>>>((const f32x4*)W, basisv, glist, cnt, part);
    k_out<<<64, 256, 0, stream>>>(part, cnt, w_fc, b_fc, out);
}

// Round 14
// 31.102 us; speedup vs baseline: 3.3799x; 1.3934x over previous
//
#include <hip/hip_runtime.h>
#include <math.h>

// B=4, N=16, K=16, H=64, O=1.  W: (a,b,d,e,k,o) fp32 = 256 MiB.
// h[z,a,o] = sum_j P[z,a,j] W[a,j,o];  P = <basis(a,b,k),basis(d,e,k)>_z
// out[z,a] = silu(h[z,a,:]) . w_fc + b_fc
//
// Cosine cutoff (dist>=5) + zero diagonal kill ~65% of W rows exactly ->
// their loads are skipped (bit-exact). R14 = R9 (best, 29.3us) plus:
//  1. PSEUDO-RANDOM BLOCK PERMUTATION item=(bi*1237)&2047: decorrelates
//     the (b,d) codes of the 8 blocks resident on one CU (R9's a*128+blk
//     mapping gave each CU a correlated sample -> max-CU ~2x mean work).
//  2. basisv TABLE (256 KB via k_basis): removes the ~800 VALU-cycle
//     transcendental prologue from every one of 2048 blocks (~5us/CU).
//
// ws (floats):
//   part   : [16][128][256] = 524,288 f @ 0        (2 MB)
//   basisv : f32x4[16384]   =  65,536 f @ 524288   (256 KB)

#define NJ 65536
#define BPA 128   // blocks per 'a' -> 2048 items

typedef float f32x4 __attribute__((ext_vector_type(4)));

static constexpr double D_START = 0.006737946999085467; // exp(-5)

__global__ void k_basis(const float* __restrict__ x, f32x4* __restrict__ basisv) {
    int t = blockIdx.x * 256 + threadIdx.x; // (z,p,q): 4*16*16 = 1024
    if (t >= 1024) return;
    int q = t & 15, p = (t >> 4) & 15, z = t >> 8;
    const float* xp = x + (z * 16 + p) * 3;
    const float* xq = x + (z * 16 + q) * 3;
    float d0 = xp[0] - xq[0], d1 = xp[1] - xq[1], d2 = xp[2] - xq[2];
    float nsq = d0 * d0 + d1 * d1 + d2 * d2 + 1e-5f;
    float nrm = sqrtf(nsq);
    f32x4* o = basisv + (size_t)t * 16;
    if (nrm >= 5.0f) {                       // cutoff kills the pair exactly
        f32x4 zv = {0.f, 0.f, 0.f, 0.f};
        #pragma unroll
        for (int k = 0; k < 16; ++k) o[k] = zv;
        return;
    }
    float cut = 0.5f * (cosf(nrm * 0.6283185307179586f) + 1.0f);
    float ex = expf(-nrm); // alpha=1, CUT_LO=0
    const float START = (float)D_START;
    const float STEP  = (float)((1.0 - D_START) / 15.0);
    const float BETA  = (float)(1.0 / ((0.125 * (1.0 - D_START)) * (0.125 * (1.0 - D_START))));
    #pragma unroll
    for (int k = 0; k < 16; ++k) {
        float m = START + STEP * (float)k;
        float dmm = ex - m;
        float s = cut * expf(-BETA * dmm * dmm) / nsq; // /nsq of diff folded in
        f32x4 v; v.x = s * d0; v.y = s * d1; v.z = s * d2; v.w = 0.f;
        o[k] = v;   // diagonal pairs: d==0 -> stored basis is exactly 0
    }
}

__global__ __launch_bounds__(256) void k_main(const f32x4* __restrict__ W4,
                                              const f32x4* __restrict__ basisv,
                                              float* __restrict__ part) {
    // decorrelating bijection over the 2048 work items
    unsigned item = (blockIdx.x * 1237u) & 2047u;
    int a   = (int)(item >> 7);
    int blk = (int)(item & (BPA - 1)); // (b, d-pair)

    __shared__ f32x4 p_lds[512];
    __shared__ float red[4][256];

    // ---- prologue: P for this item's 512 j-rows, from the basisv table ----
    int t = threadIdx.x;
    f32x4 p0, p1;
    {
        int e = t >> 4, k = t & 15;
        int b = blk >> 3, dd = (blk & 7) * 2;
        #pragma unroll
        for (int z = 0; z < 4; ++z) {
            f32x4 u  = basisv[(z * 256 + a * 16 + b) * 16 + k];
            f32x4 v0 = basisv[(z * 256 + dd * 16 + e) * 16 + k];
            f32x4 v1 = basisv[(z * 256 + (dd + 1) * 16 + e) * 16 + k];
            p0[z] = u.x * v0.x + u.y * v0.y + u.z * v0.z;
            p1[z] = u.x * v1.x + u.y * v1.y + u.z * v1.z;
        }
    }
    bool f0 = (fabsf(p0.x) + fabsf(p0.y) + fabsf(p0.z) + fabsf(p0.w)) != 0.0f;
    bool f1 = (fabsf(p1.x) + fabsf(p1.y) + fabsf(p1.z) + fabsf(p1.w)) != 0.0f;
    unsigned long long bal0 = __ballot(f0);  // rows [w*64, w*64+64)
    unsigned long long bal1 = __ballot(f1);  // rows [256+w*64, ...)
    p_lds[t]       = p0;
    p_lds[t + 256] = p1;
    __syncthreads();

    int wave = threadIdx.x >> 6;
    int lane = threadIdx.x & 63;
    int og   = lane & 15;  // group of 4 'o' columns
    int rsub = lane >> 4;  // row within the 4-row group

    // group mask: bits 0..7 = A-half groups, 8..15 = B-half groups
    unsigned mask = 0;
    #pragma unroll
    for (int g = 0; g < 8; ++g) {
        if ((bal0 >> (8 * g)) & 0xFFull) mask |= 1u << g;
        if ((bal1 >> (8 * g)) & 0xFFull) mask |= 1u << (g + 8);
    }

    float acc[4][4] = {{0.f, 0.f, 0.f, 0.f}, {0.f, 0.f, 0.f, 0.f},
                       {0.f, 0.f, 0.f, 0.f}, {0.f, 0.f, 0.f, 0.f}};
    size_t rowbase = (size_t)a * NJ + (size_t)blk * 512;
    while (mask) {  // wave-uniform: mask derived from ballots
        int g = __builtin_ctz(mask);
        mask &= mask - 1;
        int rloc = ((g & 8) ? 256 : 0) + wave * 64 + (g & 7) * 8 + rsub;
        f32x4 pA = p_lds[rloc];
        f32x4 pB = p_lds[rloc + 4];
        f32x4 wA = W4[(rowbase + rloc) * 16 + og];       // 1 KB contiguous/wave
        f32x4 wB = W4[(rowbase + rloc + 4) * 16 + og];   // 1 KB contiguous/wave
        acc[0][0] += pA.x * wA.x + pB.x * wB.x; acc[0][1] += pA.x * wA.y + pB.x * wB.y;
        acc[0][2] += pA.x * wA.z + pB.x * wB.z; acc[0][3] += pA.x * wA.w + pB.x * wB.w;
        acc[1][0] += pA.y * wA.x + pB.y * wB.x; acc[1][1] += pA.y * wA.y + pB.y * wB.y;
        acc[1][2] += pA.y * wA.z + pB.y * wB.z; acc[1][3] += pA.y * wA.w + pB.y * wB.w;
        acc[2][0] += pA.z * wA.x + pB.z * wB.x; acc[2][1] += pA.z * wA.y + pB.z * wB.y;
        acc[2][2] += pA.z * wA.z + pB.z * wB.z; acc[2][3] += pA.z * wA.w + pB.z * wB.w;
        acc[3][0] += pA.w * wA.x + pB.w * wB.x; acc[3][1] += pA.w * wA.y + pB.w * wB.y;
        acc[3][2] += pA.w * wA.z + pB.w * wB.z; acc[3][3] += pA.w * wA.w + pB.w * wB.w;
    }
    // reduce across the 4 row-subgroups (lane bits 4,5)
    #pragma unroll
    for (int z = 0; z < 4; ++z) {
        #pragma unroll
        for (int c = 0; c < 4; ++c) {
            float v = acc[z][c];
            v += __shfl_xor(v, 16);
            v += __shfl_xor(v, 32);
            acc[z][c] = v;
        }
    }
    if (rsub == 0) {
        #pragma unroll
        for (int z = 0; z < 4; ++z) {
            #pragma unroll
            for (int c = 0; c < 4; ++c)
                red[wave][z * 64 + og * 4 + c] = acc[z][c];
        }
    }
    __syncthreads();
    // (z*64 + o) = t
    float s = red[0][t] + red[1][t] + red[2][t] + red[3][t];
    part[((size_t)a * BPA + blk) * 256 + t] = s;
}

__global__ void k_out(const float* __restrict__ part, const float* __restrict__ w_fc,
                      const float* __restrict__ b_fc, float* __restrict__ out) {
    // one block per (z,a); 256 threads = 4 blk-quarters x 64 'o'
    int z = blockIdx.x >> 4, a = blockIdx.x & 15;
    int o = threadIdx.x & 63, bq = threadIdx.x >> 6;
    float s = 0.f;
    for (int blk = bq; blk < BPA; blk += 4)
        s += part[((size_t)a * BPA + blk) * 256 + z * 64 + o]; // coalesced over o
    __shared__ float red[4][64];
    red[bq][o] = s;
    __syncthreads();
    if (threadIdx.x < 64) {
        float h = red[0][o] + red[1][o] + red[2][o] + red[3][o];
        float v = h * (1.0f / (1.0f + expf(-h))) * w_fc[o]; // silu * weight
        #pragma unroll
        for (int off = 32; off >= 1; off >>= 1) v += __shfl_xor(v, off);
        if (o == 0) out[z * 16 + a] = v + b_fc[0];
    }
}

extern "C" void kernel_launch(void* const* d_in, const int* in_sizes, int n_in,
                              void* d_out, int out_size, void* d_ws, size_t ws_size,
                              hipStream_t stream) {
    const float* x    = (const float*)d_in[0];
    const float* W    = (const float*)d_in[1];
    const float* w_fc = (const float*)d_in[2];
    const float* b_fc = (const float*)d_in[3];
    float* ws  = (float*)d_ws;
    float* out = (float*)d_out;

    float* part   = ws;                     // 524,288 floats
    f32x4* basisv = (f32x4*)(ws + 524288);  // 65,536 floats

    k_basis<<<4, 256, 0, stream>>>(x, basisv);
    k_main<<<16 * BPA, 256, 0, stream>>>((const f32x4*)W, basisv, part);
    k_out<<<64, 256, 0, stream>>>(part, w_fc, b_fc, out);
}

// Round 15
// 30.531 us; speedup vs baseline: 3.4431x; 1.0187x over previous
//
#include <hip/hip_runtime.h>
#include <math.h>

// B=4, N=16, K=16, H=64, O=1.  W: (a,b,d,e,k,o) fp32 = 256 MiB.
// h[z,a,o] = sum_j P[z,a,j] W[a,j,o];  P = <basis(a,b,k),basis(d,e,k)>_z
// out[z,a] = silu(h[z,a,:]) . w_fc + b_fc
//
// Cosine cutoff (dist>=5) + zero diagonal kill ~73% of W rows exactly ->
// their loads are skipped (bit-exact). R15 = R9 structure (sequential
// block->item mapping, best measured) + basisv table (R14, verified
// bit-exact) + HAND-PIPELINED mask loop: next group's W loads issue
// before current group's FMAs, so the wave keeps 4 KB in flight
// (compiler emits vmcnt(2) instead of vmcnt(0) before the FMAs).
//
// ws (floats):
//   part   : [16][128][256] = 524,288 f @ 0        (2 MB)
//   basisv : f32x4[16384]   =  65,536 f @ 524288   (256 KB)

#define NJ 65536
#define BPA 128   // blocks per 'a' -> 2048 items

typedef float f32x4 __attribute__((ext_vector_type(4)));

static constexpr double D_START = 0.006737946999085467; // exp(-5)

#define ACC8(pA, pB, wA, wB) do {                                              \
    acc[0][0] += pA.x * wA.x + pB.x * wB.x; acc[0][1] += pA.x * wA.y + pB.x * wB.y; \
    acc[0][2] += pA.x * wA.z + pB.x * wB.z; acc[0][3] += pA.x * wA.w + pB.x * wB.w; \
    acc[1][0] += pA.y * wA.x + pB.y * wB.x; acc[1][1] += pA.y * wA.y + pB.y * wB.y; \
    acc[1][2] += pA.y * wA.z + pB.y * wB.z; acc[1][3] += pA.y * wA.w + pB.y * wB.w; \
    acc[2][0] += pA.z * wA.x + pB.z * wB.x; acc[2][1] += pA.z * wA.y + pB.z * wB.y; \
    acc[2][2] += pA.z * wA.z + pB.z * wB.z; acc[2][3] += pA.z * wA.w + pB.z * wB.w; \
    acc[3][0] += pA.w * wA.x + pB.w * wB.x; acc[3][1] += pA.w * wA.y + pB.w * wB.y; \
    acc[3][2] += pA.w * wA.z + pB.w * wB.z; acc[3][3] += pA.w * wA.w + pB.w * wB.w; \
} while (0)

__global__ void k_basis(const float* __restrict__ x, f32x4* __restrict__ basisv) {
    int t = blockIdx.x * 256 + threadIdx.x; // (z,p,q): 4*16*16 = 1024
    if (t >= 1024) return;
    int q = t & 15, p = (t >> 4) & 15, z = t >> 8;
    const float* xp = x + (z * 16 + p) * 3;
    const float* xq = x + (z * 16 + q) * 3;
    float d0 = xp[0] - xq[0], d1 = xp[1] - xq[1], d2 = xp[2] - xq[2];
    float nsq = d0 * d0 + d1 * d1 + d2 * d2 + 1e-5f;
    float nrm = sqrtf(nsq);
    f32x4* o = basisv + (size_t)t * 16;
    if (nrm >= 5.0f) {                       // cutoff kills the pair exactly
        f32x4 zv = {0.f, 0.f, 0.f, 0.f};
        #pragma unroll
        for (int k = 0; k < 16; ++k) o[k] = zv;
        return;
    }
    float cut = 0.5f * (cosf(nrm * 0.6283185307179586f) + 1.0f);
    float ex = expf(-nrm); // alpha=1, CUT_LO=0
    const float START = (float)D_START;
    const float STEP  = (float)((1.0 - D_START) / 15.0);
    const float BETA  = (float)(1.0 / ((0.125 * (1.0 - D_START)) * (0.125 * (1.0 - D_START))));
    #pragma unroll
    for (int k = 0; k < 16; ++k) {
        float m = START + STEP * (float)k;
        float dmm = ex - m;
        float s = cut * expf(-BETA * dmm * dmm) / nsq; // /nsq of diff folded in
        f32x4 v; v.x = s * d0; v.y = s * d1; v.z = s * d2; v.w = 0.f;
        o[k] = v;   // diagonal pairs: diff==0 -> stored basis is exactly 0
    }
}

__global__ __launch_bounds__(256) void k_main(const f32x4* __restrict__ W4,
                                              const f32x4* __restrict__ basisv,
                                              float* __restrict__ part) {
    int a   = blockIdx.x >> 7;        // sequential mapping (R9; best)
    int blk = blockIdx.x & (BPA - 1); // (b, d-pair)

    __shared__ f32x4 p_lds[512];
    __shared__ float red[4][256];

    // ---- prologue: P for this item's 512 j-rows, from the basisv table ----
    int t = threadIdx.x;
    f32x4 p0, p1;
    {
        int e = t >> 4, k = t & 15;
        int b = blk >> 3, dd = (blk & 7) * 2;
        #pragma unroll
        for (int z = 0; z < 4; ++z) {
            f32x4 u  = basisv[(z * 256 + a * 16 + b) * 16 + k];
            f32x4 v0 = basisv[(z * 256 + dd * 16 + e) * 16 + k];
            f32x4 v1 = basisv[(z * 256 + (dd + 1) * 16 + e) * 16 + k];
            p0[z] = u.x * v0.x + u.y * v0.y + u.z * v0.z;
            p1[z] = u.x * v1.x + u.y * v1.y + u.z * v1.z;
        }
    }
    bool f0 = (fabsf(p0.x) + fabsf(p0.y) + fabsf(p0.z) + fabsf(p0.w)) != 0.0f;
    bool f1 = (fabsf(p1.x) + fabsf(p1.y) + fabsf(p1.z) + fabsf(p1.w)) != 0.0f;
    unsigned long long bal0 = __ballot(f0);  // rows [w*64, w*64+64)
    unsigned long long bal1 = __ballot(f1);  // rows [256+w*64, ...)
    p_lds[t]       = p0;
    p_lds[t + 256] = p1;
    __syncthreads();

    int wave = threadIdx.x >> 6;
    int lane = threadIdx.x & 63;
    int og   = lane & 15;  // group of 4 'o' columns
    int rsub = lane >> 4;  // row within the 4-row group

    // group mask: bits 0..7 = A-half groups, 8..15 = B-half groups
    unsigned mask = 0;
    #pragma unroll
    for (int g = 0; g < 8; ++g) {
        if ((bal0 >> (8 * g)) & 0xFFull) mask |= 1u << g;
        if ((bal1 >> (8 * g)) & 0xFFull) mask |= 1u << (g + 8);
    }

    float acc[4][4] = {{0.f, 0.f, 0.f, 0.f}, {0.f, 0.f, 0.f, 0.f},
                       {0.f, 0.f, 0.f, 0.f}, {0.f, 0.f, 0.f, 0.f}};
    size_t rowbase = (size_t)a * NJ + (size_t)blk * 512;

    // ---- hand-pipelined skip loop: issue group g+1's loads before
    //      consuming group g's (keeps 4 KB in flight per wave) ----
    if (mask) {
        int g = __builtin_ctz(mask);
        mask &= mask - 1;
        int rloc = ((g & 8) ? 256 : 0) + wave * 64 + (g & 7) * 8 + rsub;
        f32x4 pA = p_lds[rloc];
        f32x4 pB = p_lds[rloc + 4];
        f32x4 wA = W4[(rowbase + rloc) * 16 + og];
        f32x4 wB = W4[(rowbase + rloc + 4) * 16 + og];
        while (mask) {
            int g2 = __builtin_ctz(mask);
            mask &= mask - 1;
            int rloc2 = ((g2 & 8) ? 256 : 0) + wave * 64 + (g2 & 7) * 8 + rsub;
            f32x4 pA2 = p_lds[rloc2];
            f32x4 pB2 = p_lds[rloc2 + 4];
            f32x4 wA2 = W4[(rowbase + rloc2) * 16 + og];      // in flight
            f32x4 wB2 = W4[(rowbase + rloc2 + 4) * 16 + og];  // in flight
            ACC8(pA, pB, wA, wB);                             // waits vmcnt(2)
            pA = pA2; pB = pB2; wA = wA2; wB = wB2;
        }
        ACC8(pA, pB, wA, wB);
    }

    // reduce across the 4 row-subgroups (lane bits 4,5)
    #pragma unroll
    for (int z = 0; z < 4; ++z) {
        #pragma unroll
        for (int c = 0; c < 4; ++c) {
            float v = acc[z][c];
            v += __shfl_xor(v, 16);
            v += __shfl_xor(v, 32);
            acc[z][c] = v;
        }
    }
    if (rsub == 0) {
        #pragma unroll
        for (int z = 0; z < 4; ++z) {
            #pragma unroll
            for (int c = 0; c < 4; ++c)
                red[wave][z * 64 + og * 4 + c] = acc[z][c];
        }
    }
    __syncthreads();
    // (z*64 + o) = t
    float s = red[0][t] + red[1][t] + red[2][t] + red[3][t];
    part[((size_t)a * BPA + blk) * 256 + t] = s;
}

__global__ void k_out(const float* __restrict__ part, const float* __restrict__ w_fc,
                      const float* __restrict__ b_fc, float* __restrict__ out) {
    // one block per (z,a); 256 threads = 4 blk-quarters x 64 'o'
    int z = blockIdx.x >> 4, a = blockIdx.x & 15;
    int o = threadIdx.x & 63, bq = threadIdx.x >> 6;
    float s = 0.f;
    for (int blk = bq; blk < BPA; blk += 4)
        s += part[((size_t)a * BPA + blk) * 256 + z * 64 + o]; // coalesced over o
    __shared__ float red[4][64];
    red[bq][o] = s;
    __syncthreads();
    if (threadIdx.x < 64) {
        float h = red[0][o] + red[1][o] + red[2][o] + red[3][o];
        float v = h * (1.0f / (1.0f + expf(-h))) * w_fc[o]; // silu * weight
        #pragma unroll
        for (int off = 32; off >= 1; off >>= 1) v += __shfl_xor(v, off);
        if (o == 0) out[z * 16 + a] = v + b_fc[0];
    }
}

extern "C" void kernel_launch(void* const* d_in, const int* in_sizes, int n_in,
                              void* d_out, int out_size, void* d_ws, size_t ws_size,
                              hipStream_t stream) {
    const float* x    = (const float*)d_in[0];
    const float* W    = (const float*)d_in[1];
    const float* w_fc = (const float*)d_in[2];
    const float* b_fc = (const float*)d_in[3];
    float* ws  = (float*)d_ws;
    float* out = (float*)d_out;

    float* part   = ws;                     // 524,288 floats
    f32x4* basisv = (f32x4*)(ws + 524288);  // 65,536 floats

    k_basis<<<4, 256, 0, stream>>>(x, basisv);
    k_main<<<16 * BPA, 256, 0, stream>>>((const f32x4*)W, basisv, part);
    k_out<<<64, 256, 0, stream>>>(part, w_fc, b_fc, out);
}